// Round 4
// baseline (519.916 us; speedup 1.0000x reference)
//
#include <hip/hip_runtime.h>
#include <hip/hip_cooperative_groups.h>
#include <math.h>

namespace cg = cooperative_groups;

#define N_NODES 50000
#define N_EDGES 800000
#define D 128          // NODE_DIM
#define DE 10          // EDGE_DIM
#define TE 64          // edges per tile (CSR-consecutive)
#define N_TILES (N_EDGES / TE)       // 12500
#define SST 132        // 4B words per sum/m row in LDS (128 + 4 pad; 2-way = free)
#define ASTR 136       // bf16 per A row in node_gemm LDS
#define OST 520        // bf16 per out row in node_gemm LDS
#define WP2_ELEMS (4 * 32 * 64 * 8)  // 65536 bf16 (128x512 packed)
#define WEF_ELEMS (16 * 64 * 8)      // 8192 bf16 (32x256 packed, k<10 live)
#define SCAN_BLOCKS 196              // 196*256 = 50176 >= 50000
#define CSTRIDE 16     // ints per histogram bin: one 64B line per node
#define ZERO_F4 1800064              // (25.6MB agg + 1KB stats + 3.2MB counts)/16B

typedef __bf16 bf16x8 __attribute__((ext_vector_type(8)));
typedef __bf16 bf16x4 __attribute__((ext_vector_type(4)));
typedef __bf16 bf16x2 __attribute__((ext_vector_type(2)));
typedef float  f32x4  __attribute__((ext_vector_type(4)));

__device__ __forceinline__ float fast_sigmoid(float x) {
    float t = __builtin_amdgcn_exp2f(-1.44269504089f * x);
    return __builtin_amdgcn_rcpf(1.0f + t);
}
__device__ __forceinline__ float fast_softplus(float x) {
    float t = __builtin_amdgcn_exp2f(-1.44269504089f * fabsf(x));
    return fmaxf(x, 0.0f) + 0.69314718056f * __builtin_amdgcn_logf(1.0f + t);
}

// ---- cooperative CSR build: zero | pack weights | hist | scan | scatter ----
// Replaces 5 launches (memset, prep, scan_partials, scan_final, csr_scatter).
// Grid MUST be SCAN_BLOCKS (196) blocks x 256 threads (scan chunk mapping).
__global__ __launch_bounds__(256) void build_csr(
    const float* __restrict__ gw, const float* __restrict__ cw,
    const int* __restrict__ ei,
    __bf16* __restrict__ wp2, __bf16* __restrict__ wef,
    int* __restrict__ counts, int* __restrict__ bsum,
    int2* __restrict__ sde, float4* __restrict__ zbase)
{
    cg::grid_group grid = cg::this_grid();
    const int t = threadIdx.x, b = blockIdx.x;
    const int gtid = b * 256 + t;
    const int gstride = SCAN_BLOCKS * 256;   // 50176

    // P0a: zero agg | stats | counts (one contiguous region)
    const float4 z4 = make_float4(0.f, 0.f, 0.f, 0.f);
    for (int i = gtid; i < ZERO_F4; i += gstride)
        zbase[i] = z4;
    // P0b: pack node-GEMM weights (cols 0:128=gw_top,128:256=cw_top,
    //      256:384=gw_mid, 384:512=cw_mid)
    for (int idx = gtid; idx < WP2_ELEMS; idx += gstride) {
        int j    = idx & 7;
        int lane = (idx >> 3) & 63;
        int nb   = (idx >> 9) & 31;
        int kb   = idx >> 14;                 // 0..3
        int k    = kb * 32 + ((lane >> 4) << 3) + j;   // 0..127
        int jp   = nb * 16 + (lane & 15);
        float v;
        if      (jp < 128) v = gw[k * D + jp];
        else if (jp < 256) v = cw[k * D + (jp - 128)];
        else if (jp < 384) v = gw[(128 + k) * D + (jp - 256)];
        else               v = cw[(128 + k) * D + (jp - 384)];
        wp2[idx] = (__bf16)v;
    }
    // P0c: pack ef weights (32x256, k<10 live)
    if (gtid < WEF_ELEMS) {
        int idx = gtid;
        int j    = idx & 7;
        int lane = (idx >> 3) & 63;
        int nb   = idx >> 9;                  // 0..15 (even=gate, odd=cand)
        int k    = ((lane >> 4) << 3) + j;    // 0..31
        int col  = (nb >> 1) * 16 + (lane & 15);
        const float* w = (nb & 1) ? cw : gw;
        wef[idx] = (__bf16)((k < 10) ? w[(256 + k) * D + col] : 0.0f);
    }
    grid.sync();

    // P1: histogram (device-scope atomics, one 64B line per node)
    #pragma unroll 4
    for (int e = gtid; e < N_EDGES; e += gstride)
        atomicAdd(&counts[ei[e] * CSTRIDE], 1);
    grid.sync();

    // P2a: block-local inclusive scan of this block's 256 counts
    __shared__ int ss[256];
    __shared__ int sb[256];
    const int i = b * 256 + t;
    const int c = (i < N_NODES) ? counts[i * CSTRIDE] : 0;
    ss[t] = c;
    __syncthreads();
    #pragma unroll
    for (int off = 1; off < 256; off <<= 1) {
        int v = (t >= off) ? ss[t - off] : 0;
        __syncthreads();
        ss[t] += v;
        __syncthreads();
    }
    if (t == 255) bsum[b] = ss[255];
    grid.sync();

    // P2b: scan the 196 block totals, write exclusive cursor in place
    sb[t] = (t < SCAN_BLOCKS) ? bsum[t] : 0;
    __syncthreads();
    #pragma unroll
    for (int off = 1; off < 256; off <<= 1) {
        int v = (t >= off) ? sb[t - off] : 0;
        __syncthreads();
        sb[t] += v;
        __syncthreads();
    }
    int base = b ? sb[b - 1] : 0;
    if (i < N_NODES) counts[i * CSTRIDE] = base + ss[t] - c;   // exclusive prefix
    grid.sync();

    // P3: scatter into CSR order; payload {src | dst<<16, eid}
    #pragma unroll 4
    for (int e = gtid; e < N_EDGES; e += gstride) {
        int node = ei[e];
        int pos = atomicAdd(&counts[node * CSTRIDE], 1);
        sde[pos] = make_int2(node | (ei[N_EDGES + e] << 16), e);
    }
}

// ---- node projection GEMM: [50048x128] @ [128x512] -> proj (bf16) ----
// cols 0:256 -> pa (in d_out), cols 256:512 -> pb (ws, aliases dead counts).
__global__ __launch_bounds__(512, 4) void node_gemm(
    const float* __restrict__ h, const __bf16* __restrict__ wp2,
    __bf16* __restrict__ pa, __bf16* __restrict__ pb)
{
    __shared__ __align__(16) __bf16 sm[64 * OST];   // 66,560 B; A-tile aliases base
    __bf16* za = sm;                                 // [64][ASTR] in phase A
    const int t  = threadIdx.x;
    const int r0 = blockIdx.x * 64;

    #pragma unroll
    for (int it = 0; it < 4; ++it) {
        int ch  = it * 512 + t;            // 2048 float4 chunks (64 rows x 32)
        int row = ch >> 5, cs = ch & 31;
        int node = r0 + row;
        float4 v = (node < N_NODES) ? *(const float4*)&h[(size_t)node * D + cs * 4]
                                    : make_float4(0.f, 0.f, 0.f, 0.f);
        bf16x4 o = { (__bf16)v.x, (__bf16)v.y, (__bf16)v.z, (__bf16)v.w };
        *(bf16x4*)&za[row * ASTR + cs * 4] = o;
    }
    __syncthreads();

    const int w = t >> 6, l = t & 63, quad = l >> 4, col16 = l & 15;
    f32x4 acc[4][4];
    #pragma unroll
    for (int mt = 0; mt < 4; ++mt)
        #pragma unroll
        for (int nt = 0; nt < 4; ++nt)
            acc[mt][nt] = (f32x4)0.0f;

    const __bf16* zp = &za[col16 * ASTR + quad * 8];
    const __bf16* bp = &wp2[(size_t)((w * 4) * 64 + l) * 8];

    #pragma unroll
    for (int kb = 0; kb < 4; ++kb) {
        bf16x8 afr[4];
        #pragma unroll
        for (int mt = 0; mt < 4; ++mt)
            afr[mt] = *(const bf16x8*)&zp[mt * 16 * ASTR + kb * 32];
        bf16x8 bfr[4];
        #pragma unroll
        for (int nt = 0; nt < 4; ++nt)
            bfr[nt] = *(const bf16x8*)&bp[(size_t)(kb * 32 + nt) * 512];
        #pragma unroll
        for (int mt = 0; mt < 4; ++mt)
            #pragma unroll
            for (int nt = 0; nt < 4; ++nt)
                acc[mt][nt] = __builtin_amdgcn_mfma_f32_16x16x32_bf16(
                    afr[mt], bfr[nt], acc[mt][nt], 0, 0, 0);
    }
    __syncthreads();   // A dead; reuse sm as out-tile

    #pragma unroll
    for (int mt = 0; mt < 4; ++mt)
        #pragma unroll
        for (int nt = 0; nt < 4; ++nt)
            #pragma unroll
            for (int r = 0; r < 4; ++r) {
                int row  = mt * 16 + quad * 4 + r;
                int colj = (w * 4 + nt) * 16 + col16;
                sm[row * OST + colj] = (__bf16)acc[mt][nt][r];
            }
    __syncthreads();

    #pragma unroll
    for (int it = 0; it < 8; ++it) {
        int ch  = it * 512 + t;            // 4096 chunks of 8 bf16 (64 rows x 64)
        int row = ch >> 6, cc = ch & 63;
        int node = r0 + row;
        if (node < N_NODES) {
            bf16x8 v = *(const bf16x8*)&sm[row * OST + cc * 8];
            int j0 = cc * 8;
            if (j0 < 256) *(bf16x8*)&pa[(size_t)node * 256 + j0]         = v;
            else          *(bf16x8*)&pb[(size_t)node * 256 + (j0 - 256)] = v;
        }
    }
}

// ---- edge kernel (R2-proven, 112 us): gather proj sums + tiny ef-MFMA +
// activation + run-segmented scatter ----
__global__ __launch_bounds__(512, 6) void edge_fuse(
    const __bf16* __restrict__ pa, const __bf16* __restrict__ pb,
    const int2* __restrict__ sde, const float* __restrict__ ef,
    const __bf16* __restrict__ wef,
    const float* __restrict__ gb, const float* __restrict__ cb,
    float* __restrict__ agg)
{
    __shared__ __align__(16) unsigned int sbuf[TE * SST];  // 33,792 B
    __shared__ __align__(16) __bf16 zE[TE * 32];           // 4 KB
    __shared__ int s_src[TE], s_dst[TE], s_eid[TE];

    const int t  = threadIdx.x;
    const int e0 = blockIdx.x * TE;
    const int w = t >> 6, l = t & 63, quad = l >> 4, col16 = l & 15;

    // early independent loads (in flight across staging)
    const __bf16* wpp = &wef[(size_t)((w * 2) * 64 + l) * 8];
    bf16x8 bfr0 = *(const bf16x8*)&wpp[0];
    bf16x8 bfr1 = *(const bf16x8*)&wpp[512];
    const int c = w * 16 + col16;
    const float gbv = gb[c], cbv = cb[c];

    if (t < TE) {
        int2 p = sde[e0 + t];
        s_src[t] = p.x & 0xFFFF;
        s_dst[t] = (p.x >> 16) & 0xFFFF;
        s_eid[t] = p.y;
    }
    __syncthreads();

    // ef rows -> zE (k 0..9 live, 10..31 zero)
    if (t < TE) {
        const float* efr = &ef[(size_t)s_eid[t] * DE];
        __bf16* row = &zE[t * 32];
        #pragma unroll
        for (int j = 0; j < 5; ++j) {
            float2 a = *(const float2*)&efr[j * 2];
            bf16x2 p = { (__bf16)a.x, (__bf16)a.y };
            *(bf16x2*)&row[j * 2] = p;
        }
        *(bf16x2*)&row[10] = (bf16x2)(__bf16)0.0f;
        *(bf16x4*)&row[12] = (bf16x4)(__bf16)0.0f;
        *(bf16x8*)&row[16] = (bf16x8)(__bf16)0.0f;
        *(bf16x8*)&row[24] = (bf16x8)(__bf16)0.0f;
    }

    // sum staging: 1024 tasks = 64 edges x 16 col-groups of 8
    #pragma unroll
    for (int it = 0; it < 2; ++it) {
        int id  = it * 512 + t;
        int e   = id >> 4, grp = id & 15;
        int src = s_src[e], dst = s_dst[e];
        int c0  = grp * 8;
        bf16x8 ag = *(const bf16x8*)&pa[(size_t)src * 256 + c0];
        bf16x8 ac = *(const bf16x8*)&pa[(size_t)src * 256 + 128 + c0];
        bf16x8 bg = *(const bf16x8*)&pb[(size_t)dst * 256 + c0];
        bf16x8 bc = *(const bf16x8*)&pb[(size_t)dst * 256 + 128 + c0];
        unsigned int wds[8];
        #pragma unroll
        for (int j = 0; j < 8; ++j) {
            float gs = (float)ag[j] + (float)bg[j];
            float cs = (float)ac[j] + (float)bc[j];
            bf16x2 pr = { (__bf16)gs, (__bf16)cs };
            wds[j] = __builtin_bit_cast(unsigned int, pr);
        }
        *(uint4*)&sbuf[e * SST + c0]     = *(const uint4*)&wds[0];
        *(uint4*)&sbuf[e * SST + c0 + 4] = *(const uint4*)&wds[4];
    }
    __syncthreads();

    // ef @ W_ef : 8 MFMA per wave (4 row-tiles x {gate,cand})
    f32x4 acc[4][2];
    #pragma unroll
    for (int mt = 0; mt < 4; ++mt) {
        const bf16x8 a = *(const bf16x8*)&zE[(mt * 16 + col16) * 32 + quad * 8];
        acc[mt][0] = __builtin_amdgcn_mfma_f32_16x16x32_bf16(a, bfr0, (f32x4)0.0f, 0, 0, 0);
        acc[mt][1] = __builtin_amdgcn_mfma_f32_16x16x32_bf16(a, bfr1, (f32x4)0.0f, 0, 0, 0);
    }

    // activation in-place: sum word -> m (f32). Owner-exclusive slot, no barrier.
    #pragma unroll
    for (int mt = 0; mt < 4; ++mt) {
        #pragma unroll
        for (int r = 0; r < 4; ++r) {
            int e = mt * 16 + quad * 4 + r;
            unsigned int u = sbuf[e * SST + c];
            float gs = __builtin_bit_cast(float, u << 16);
            float cs = __builtin_bit_cast(float, u & 0xFFFF0000u);
            float sg = fast_sigmoid(acc[mt][0][r] + gs + gbv);
            float sp = fast_softplus(acc[mt][1][r] + cs + cbv);
            ((float*)sbuf)[e * SST + c] = sg * sp;
        }
    }
    __syncthreads();

    // run-segmented reduction, one atomic per run; 4 segs x 128 cols
    const int seg = t >> 7;
    const int cc  = t & 127;
    const int rlo = seg * 16, rhi = rlo + 16;
    int   cur = s_src[rlo];
    float s   = 0.0f;
    const float* ms = (const float*)sbuf;
    for (int e = rlo; e < rhi; ++e) {
        int node = s_src[e];
        float v  = ms[e * SST + cc];
        if (node != cur) {
            atomicAdd(&agg[(size_t)cur * D + cc], s);
            s = 0.0f; cur = node;
        }
        s += v;
    }
    atomicAdd(&agg[(size_t)cur * D + cc], s);
}

// ---- cooperative finish: col_stats + grid.sync + BN-fold + softplus ----
__global__ __launch_bounds__(256) void finish(
    const float* __restrict__ h, const float* __restrict__ agg,
    float* __restrict__ stats, const float* __restrict__ gamma,
    const float* __restrict__ beta, float* __restrict__ out)
{
    cg::grid_group grid = cg::this_grid();
    const int t = threadIdx.x;

    // phase A: column sums/sumsq (stats zeroed in build_csr, untouched since)
    {
        const int col  = t & 127;
        const int half = t >> 7;
        float s = 0.0f, s2 = 0.0f;
        for (int r = blockIdx.x * 2 + half; r < N_NODES; r += gridDim.x * 2) {
            float v = agg[(size_t)r * D + col];
            s += v; s2 += v * v;
        }
        atomicAdd(&stats[col], s);
        atomicAdd(&stats[128 + col], s2);
    }
    grid.sync();

    // phase B: out = softplus(h + agg*scale + bias)
    __shared__ float sc[128], bi[128];
    if (t < 128) {
        const float inv_n = 1.0f / (float)N_NODES;
        float mean = stats[t] * inv_n;
        float var  = stats[128 + t] * inv_n - mean * mean;
        var = fmaxf(var, 0.0f);
        float rstd = rsqrtf(var + 1e-5f);
        float s = rstd * gamma[t];
        sc[t] = s;
        bi[t] = beta[t] - mean * s;
    }
    __syncthreads();
    const int total4 = N_NODES * D / 4;
    for (int idx4 = blockIdx.x * 256 + t; idx4 < total4; idx4 += gridDim.x * 256) {
        int base = idx4 * 4;
        float4 hv = *(const float4*)&h[base];
        float4 av = *(const float4*)&agg[base];
        int cc = base & 127;
        float4 o;
        o.x = fast_softplus(hv.x + av.x * sc[cc + 0] + bi[cc + 0]);
        o.y = fast_softplus(hv.y + av.y * sc[cc + 1] + bi[cc + 1]);
        o.z = fast_softplus(hv.z + av.z * sc[cc + 2] + bi[cc + 2]);
        o.w = fast_softplus(hv.w + av.w * sc[cc + 3] + bi[cc + 3]);
        *(float4*)&out[base] = o;
    }
}

extern "C" void kernel_launch(void* const* d_in, const int* in_sizes, int n_in,
                              void* d_out, int out_size, void* d_ws, size_t ws_size,
                              hipStream_t stream) {
    const float* h     = (const float*)d_in[0];
    const int*   ei    = (const int*)  d_in[1];
    const float* ef    = (const float*)d_in[2];
    const float* gw    = (const float*)d_in[3];
    const float* gb    = (const float*)d_in[4];
    const float* cw    = (const float*)d_in[5];
    const float* cb    = (const float*)d_in[6];
    const float* gamma = (const float*)d_in[7];
    const float* beta  = (const float*)d_in[8];
    float* out = (float*)d_out;

    // Layout: [agg 25.6M][stats 1K][U: counts 3.2M + bsum -> later pb 25.6M]
    //         [wp2 128K][wef 16K][sde 6.4M]   (~57.75 MB total, proven in R2)
    float*  agg    = (float*)d_ws;
    float*  stats  = agg + (size_t)N_NODES * D;
    int*    counts = (int*)(stats + 256);                    // U base
    int*    bsum   = counts + N_NODES * CSTRIDE;
    __bf16* pb     = (__bf16*)counts;                        // aliases U after build_csr
    char*   afterU = (char*)counts + (size_t)N_NODES * 256 * sizeof(__bf16);  // 25.6MB
    __bf16* wp2    = (__bf16*)afterU;                        // 128 KB
    __bf16* wef    = wp2 + WP2_ELEMS;                        // 16 KB
    int2*   sde    = (int2*)(wef + WEF_ELEMS);               // 6.4 MB
    __bf16* pa     = (__bf16*)d_out;                         // scratch until finish
    float4* zbase  = (float4*)d_ws;

    // K1: cooperative build (zero + pack + hist + scan + scatter)
    {
        void* args[] = { (void*)&gw, (void*)&cw, (void*)&ei, (void*)&wp2,
                         (void*)&wef, (void*)&counts, (void*)&bsum,
                         (void*)&sde, (void*)&zbase };
        hipLaunchCooperativeKernel((const void*)build_csr,
                                   dim3(SCAN_BLOCKS), dim3(256), args, 0, stream);
    }
    // K2: node projection GEMM (counts dead after K1: pb alias safe)
    node_gemm<<<(N_NODES + 63) / 64, 512, 0, stream>>>(h, wp2, pa, pb);
    // K3: edge fuse (R2-proven)
    edge_fuse<<<N_TILES, 512, 0, stream>>>(pa, pb, sde, ef, wef, gb, cb, agg);
    // K4: cooperative finish (col_stats + out_softplus)
    {
        void* args[] = { (void*)&h, (void*)&agg, (void*)&stats,
                         (void*)&gamma, (void*)&beta, (void*)&out };
        hipLaunchCooperativeKernel((const void*)finish,
                                   dim3(784), dim3(256), args, 0, stream);
    }
}

// Round 6
// 346.548 us; speedup vs baseline: 1.5003x; 1.5003x over previous
//
#include <hip/hip_runtime.h>
#include <math.h>

#define N_NODES 50000
#define N_EDGES 800000
#define D 128          // NODE_DIM
#define DE 10          // EDGE_DIM
#define TE 64          // edges per tile (CSR-consecutive)
#define N_TILES (N_EDGES / TE)       // 12500
#define SST 132        // f32 words per m row in LDS (128 + 4 pad; 2-way = free)
#define ASTR 136       // bf16 per A row in node_gemm LDS
#define OST 520        // bf16 per out row in node_gemm LDS
#define WP2_ELEMS (4 * 32 * 64 * 8)  // 65536 bf16 (128x512 packed)
#define WEF_ELEMS (16 * 64 * 8)      // 8192 bf16 (32x256 packed, k<10 live)
#define SCAN_BLOCKS 196              // 196*256 = 50176 >= 50000
#define CSTRIDE 16     // ints per histogram bin: one 64B line per node
#define SCAT_BLOCKS 1563             // ceil(800000/512)
#define GEMM_BLOCKS 782              // ceil(50000/64)

typedef __bf16 bf16x8 __attribute__((ext_vector_type(8)));
typedef __bf16 bf16x4 __attribute__((ext_vector_type(4)));
typedef __bf16 bf16x2 __attribute__((ext_vector_type(2)));
typedef float  f32x4  __attribute__((ext_vector_type(4)));

__device__ __forceinline__ float fast_sigmoid(float x) {
    float t = __builtin_amdgcn_exp2f(-1.44269504089f * x);
    return __builtin_amdgcn_rcpf(1.0f + t);
}
__device__ __forceinline__ float fast_softplus(float x) {
    float t = __builtin_amdgcn_exp2f(-1.44269504089f * fabsf(x));
    return fmaxf(x, 0.0f) + 0.69314718056f * __builtin_amdgcn_logf(1.0f + t);
}
// low/high bf16 of a packed u32 -> f32 (1 VALU each)
__device__ __forceinline__ float bflo(unsigned int u) {
    return __builtin_bit_cast(float, u << 16);
}
__device__ __forceinline__ float bfhi(unsigned int u) {
    return __builtin_bit_cast(float, u & 0xFFFF0000u);
}

// ---- prep: pack node-GEMM weights | pack ef weights | hist + rank capture ----
// [0,256) wp2; [256,288) wef; [288,3413) hist.
// wp2 logical cols: 0:128=gw_top, 128:256=cw_top, 256:384=gw_mid, 384:512=cw_mid.
// hist: the atomicAdd return value IS the edge's rank within its node — persist
// it (ushort, coalesced) so the scatter pass needs NO atomics. Max degree for
// this input ~ Poisson(16) << 65535.
__global__ __launch_bounds__(256) void prep(
    const float* __restrict__ gw, const float* __restrict__ cw,
    const int* __restrict__ ei,
    __bf16* __restrict__ wp2, __bf16* __restrict__ wef,
    int* __restrict__ counts, unsigned short* __restrict__ rank)
{
    int bx = blockIdx.x, t = threadIdx.x;
    if (bx < 256) {
        int idx = bx * 256 + t;               // < 65536
        int j    = idx & 7;
        int lane = (idx >> 3) & 63;
        int nb   = (idx >> 9) & 31;
        int kb   = idx >> 14;                 // 0..3
        int k    = kb * 32 + ((lane >> 4) << 3) + j;   // 0..127
        int jp   = nb * 16 + (lane & 15);
        float v;
        if      (jp < 128) v = gw[k * D + jp];
        else if (jp < 256) v = cw[k * D + (jp - 128)];
        else if (jp < 384) v = gw[(128 + k) * D + (jp - 256)];
        else               v = cw[(128 + k) * D + (jp - 384)];
        wp2[idx] = (__bf16)v;
    } else if (bx < 288) {
        int idx = (bx - 256) * 256 + t;       // < 8192
        int j    = idx & 7;
        int lane = (idx >> 3) & 63;
        int nb   = idx >> 9;                  // 0..15 (even=gate, odd=cand)
        int k    = ((lane >> 4) << 3) + j;    // 0..31
        int col  = (nb >> 1) * 16 + (lane & 15);
        const float* w = (nb & 1) ? cw : gw;
        wef[idx] = (__bf16)((k < 10) ? w[(256 + k) * D + col] : 0.0f);
    } else {
        int e = (bx - 288) * 256 + t;         // exact: 3125*256 = 800000
        int r = atomicAdd(&counts[ei[e] * CSTRIDE], 1);
        rank[e] = (unsigned short)r;
    }
}

__global__ __launch_bounds__(256) void scan_partials(
    const int* __restrict__ counts, int* __restrict__ bsum)
{
    __shared__ int ss[256];
    int t = threadIdx.x;
    int i = blockIdx.x * 256 + t;
    int c = (i < N_NODES) ? counts[i * CSTRIDE] : 0;
    ss[t] = c;
    __syncthreads();
    #pragma unroll
    for (int off = 1; off < 256; off <<= 1) {
        int v = (t >= off) ? ss[t - off] : 0;
        __syncthreads();
        ss[t] += v;
        __syncthreads();
    }
    if (t == 255) bsum[blockIdx.x] = ss[255];
}

// Writes COMPACT exclusive prefix (excl). counts is dead after this kernel,
// so the pb projection buffer can alias it in the next launch.
__global__ __launch_bounds__(256) void scan_final(
    const int* __restrict__ counts, const int* __restrict__ bsum,
    int* __restrict__ excl)
{
    __shared__ int sb[256];
    __shared__ int ss[256];
    int t = threadIdx.x;
    sb[t] = (t < SCAN_BLOCKS) ? bsum[t] : 0;
    int i = blockIdx.x * 256 + t;
    int c = (i < N_NODES) ? counts[i * CSTRIDE] : 0;
    ss[t] = c;
    __syncthreads();
    #pragma unroll
    for (int off = 1; off < 256; off <<= 1) {
        int v  = (t >= off) ? ss[t - off] : 0;
        int vb = (t >= off) ? sb[t - off] : 0;
        __syncthreads();
        ss[t] += v;
        sb[t] += vb;
        __syncthreads();
    }
    int base = blockIdx.x ? sb[blockIdx.x - 1] : 0;
    if (i < N_NODES) excl[i] = base + ss[t] - c;
}

// ---- fused launch: atomic-free CSR scatter (blocks [0,1563)) runs
// concurrently with the node projection GEMM (blocks [1563,2345)).
// Safe because: scatter touches {ei, rank, excl, perm} only; gemm writes
// pbI over the DEAD counts region + paI in d_out. ----
__global__ __launch_bounds__(512, 4) void scatter_gemm(
    const int* __restrict__ ei, const unsigned short* __restrict__ rank,
    const int* __restrict__ excl, int* __restrict__ perm,
    const float* __restrict__ h, const __bf16* __restrict__ wp2,
    unsigned int* __restrict__ paI, unsigned int* __restrict__ pbI)
{
    if (blockIdx.x < SCAT_BLOCKS) {
        int e = blockIdx.x * 512 + threadIdx.x;
        if (e < N_EDGES) {
            int node = ei[e];
            perm[excl[node] + (int)rank[e]] = e;   // no atomics: rank is unique
        }
        return;
    }

    // ---- node projection GEMM: [50048x128] @ [128x512] ----
    // Output INTERLEAVED: paI[n][c] = u32(bf16 gate_top_c, bf16 cand_top_c),
    // pbI[n][c] likewise for the mid (dst-side) halves. One u32 per (node,col)
    // gives edge_fuse a single aligned load for both gate and cand.
    __shared__ __align__(16) __bf16 sm[64 * OST];   // 66,560 B; A-tile aliases base
    __bf16* za = sm;                                 // [64][ASTR] in phase A
    const int t  = threadIdx.x;
    const int r0 = (blockIdx.x - SCAT_BLOCKS) * 64;

    #pragma unroll
    for (int it = 0; it < 4; ++it) {
        int ch  = it * 512 + t;            // 2048 float4 chunks (64 rows x 32)
        int row = ch >> 5, cs = ch & 31;
        int node = r0 + row;
        float4 v = (node < N_NODES) ? *(const float4*)&h[(size_t)node * D + cs * 4]
                                    : make_float4(0.f, 0.f, 0.f, 0.f);
        bf16x4 o = { (__bf16)v.x, (__bf16)v.y, (__bf16)v.z, (__bf16)v.w };
        *(bf16x4*)&za[row * ASTR + cs * 4] = o;
    }
    __syncthreads();

    const int w = t >> 6, l = t & 63, quad = l >> 4, col16 = l & 15;
    f32x4 acc[4][4];
    #pragma unroll
    for (int mt = 0; mt < 4; ++mt)
        #pragma unroll
        for (int nt = 0; nt < 4; ++nt)
            acc[mt][nt] = (f32x4)0.0f;

    const __bf16* zp = &za[col16 * ASTR + quad * 8];
    const __bf16* bp = &wp2[(size_t)((w * 4) * 64 + l) * 8];

    #pragma unroll
    for (int kb = 0; kb < 4; ++kb) {
        bf16x8 afr[4];
        #pragma unroll
        for (int mt = 0; mt < 4; ++mt)
            afr[mt] = *(const bf16x8*)&zp[mt * 16 * ASTR + kb * 32];
        bf16x8 bfr[4];
        #pragma unroll
        for (int nt = 0; nt < 4; ++nt)
            bfr[nt] = *(const bf16x8*)&bp[(size_t)(kb * 32 + nt) * 512];
        #pragma unroll
        for (int mt = 0; mt < 4; ++mt)
            #pragma unroll
            for (int nt = 0; nt < 4; ++nt)
                acc[mt][nt] = __builtin_amdgcn_mfma_f32_16x16x32_bf16(
                    afr[mt], bfr[nt], acc[mt][nt], 0, 0, 0);
    }
    __syncthreads();   // A dead; reuse sm as out-tile

    #pragma unroll
    for (int mt = 0; mt < 4; ++mt)
        #pragma unroll
        for (int nt = 0; nt < 4; ++nt)
            #pragma unroll
            for (int r = 0; r < 4; ++r) {
                int row  = mt * 16 + quad * 4 + r;
                int colj = (w * 4 + nt) * 16 + col16;
                sm[row * OST + colj] = (__bf16)acc[mt][nt][r];
            }
    __syncthreads();

    // epilogue: interleave (gate, cand) pairs and store 16B chunks
    #pragma unroll
    for (int it = 0; it < 8; ++it) {
        int ch   = it * 512 + t;           // 4096 chunks of 4 u32 (16B)
        int row  = ch >> 6;
        int sub  = ch & 63;
        int hp   = sub >> 5;               // 0 = paI (top), 1 = pbI (mid)
        int c0   = (sub & 31) * 4;
        int node = r0 + row;
        if (node < N_NODES) {
            const __bf16* sr = &sm[row * OST + hp * 256];
            bf16x4 gl = *(const bf16x4*)&sr[c0];
            bf16x4 cl = *(const bf16x4*)&sr[128 + c0];
            unsigned int wds[4];
            #pragma unroll
            for (int i = 0; i < 4; ++i) {
                bf16x2 pr = { gl[i], cl[i] };
                wds[i] = __builtin_bit_cast(unsigned int, pr);
            }
            unsigned int* dp = hp ? pbI : paI;
            *(uint4*)&dp[(size_t)node * 128 + c0] = *(const uint4*)&wds[0];
        }
    }
}

// ---- edge kernel: tiny ef-MFMA + DIRECT interleaved gather + activation +
// run-segmented scatter. The R2 staging loop (unpack->add->repack->LDS->
// re-read) is deleted: thread (col c, edge e) loads paI[src][c]/pbI[dst][c]
// (one u32 = gate+cand) straight from L2 and sums in f32 registers.
// 16 consecutive col16 lanes hit one aligned 64B line per quad-edge. ----
__global__ __launch_bounds__(512, 6) void edge_fuse(
    const unsigned int* __restrict__ paI, const unsigned int* __restrict__ pbI,
    const int* __restrict__ perm, const int* __restrict__ ei,
    const float* __restrict__ ef, const __bf16* __restrict__ wef,
    const float* __restrict__ gb, const float* __restrict__ cb,
    float* __restrict__ agg)
{
    __shared__ __align__(16) float ms[TE * SST];    // 33,792 B
    __shared__ __align__(16) __bf16 zE[TE * 32];    // 4 KB
    __shared__ int s_src[TE], s_dst[TE];

    const int t  = threadIdx.x;
    const int e0 = blockIdx.x * TE;
    const int w = t >> 6, l = t & 63, quad = l >> 4, col16 = l & 15;

    // early independent loads (in flight across the header)
    const __bf16* wpp = &wef[(size_t)((w * 2) * 64 + l) * 8];
    bf16x8 bfr0 = *(const bf16x8*)&wpp[0];
    bf16x8 bfr1 = *(const bf16x8*)&wpp[512];
    const int c = w * 16 + col16;
    const float gbv = gb[c], cbv = cb[c];

    if (t < TE) {
        int p = perm[e0 + t];
        s_src[t] = ei[p];
        s_dst[t] = ei[N_EDGES + p];
        // ef row -> zE (k 0..9 live, 10..31 zero)
        const float* efr = &ef[(size_t)p * DE];
        __bf16* row = &zE[t * 32];
        #pragma unroll
        for (int j = 0; j < 5; ++j) {
            float2 a = *(const float2*)&efr[j * 2];
            bf16x2 pr = { (__bf16)a.x, (__bf16)a.y };
            *(bf16x2*)&row[j * 2] = pr;
        }
        *(bf16x2*)&row[10] = (bf16x2)(__bf16)0.0f;
        *(bf16x4*)&row[12] = (bf16x4)(__bf16)0.0f;
        *(bf16x8*)&row[16] = (bf16x8)(__bf16)0.0f;
        *(bf16x8*)&row[24] = (bf16x8)(__bf16)0.0f;
    }
    __syncthreads();

    // ef @ W_ef : 8 MFMA per wave (4 row-tiles x {gate,cand})
    f32x4 acc[4][2];
    #pragma unroll
    for (int mt = 0; mt < 4; ++mt) {
        const bf16x8 a = *(const bf16x8*)&zE[(mt * 16 + col16) * 32 + quad * 8];
        acc[mt][0] = __builtin_amdgcn_mfma_f32_16x16x32_bf16(a, bfr0, (f32x4)0.0f, 0, 0, 0);
        acc[mt][1] = __builtin_amdgcn_mfma_f32_16x16x32_bf16(a, bfr1, (f32x4)0.0f, 0, 0, 0);
    }

    // direct gather + activation, per-mt batches of 8 loads (VGPR-friendly)
    #pragma unroll
    for (int mt = 0; mt < 4; ++mt) {
        unsigned int uA[4], uB[4];
        #pragma unroll
        for (int r = 0; r < 4; ++r) {
            int e = mt * 16 + quad * 4 + r;
            uA[r] = paI[(size_t)s_src[e] * 128 + c];
            uB[r] = pbI[(size_t)s_dst[e] * 128 + c];
        }
        #pragma unroll
        for (int r = 0; r < 4; ++r) {
            int e = mt * 16 + quad * 4 + r;
            float g = bflo(uA[r]) + bflo(uB[r]) + acc[mt][0][r] + gbv;
            float x = bfhi(uA[r]) + bfhi(uB[r]) + acc[mt][1][r] + cbv;
            ms[e * SST + c] = fast_sigmoid(g) * fast_softplus(x);
        }
    }
    __syncthreads();

    // run-segmented reduction, one atomic per run; 4 segs x 128 cols
    const int seg = t >> 7;
    const int cc  = t & 127;
    const int rlo = seg * 16, rhi = rlo + 16;
    int   cur = s_src[rlo];
    float s   = 0.0f;
    for (int e = rlo; e < rhi; ++e) {
        int node = s_src[e];
        float v  = ms[e * SST + cc];
        if (node != cur) {
            atomicAdd(&agg[(size_t)cur * D + cc], s);
            s = 0.0f; cur = node;
        }
        s += v;
    }
    atomicAdd(&agg[(size_t)cur * D + cc], s);
}

__global__ __launch_bounds__(256) void col_stats(
    const float* __restrict__ agg, float* __restrict__ stats)
{
    const int t    = threadIdx.x;
    const int col  = t & 127;
    const int half = t >> 7;
    float s = 0.0f, s2 = 0.0f;
    for (int r = blockIdx.x * 2 + half; r < N_NODES; r += gridDim.x * 2) {
        float v = agg[(size_t)r * D + col];
        s += v; s2 += v * v;
    }
    atomicAdd(&stats[col], s);
    atomicAdd(&stats[128 + col], s2);
}

__global__ __launch_bounds__(256) void out_softplus(
    const float* __restrict__ h, const float* __restrict__ agg,
    const float* __restrict__ stats, const float* __restrict__ gamma,
    const float* __restrict__ beta, float* __restrict__ out)
{
    __shared__ float sc[128], bi[128];
    int t = threadIdx.x;
    if (t < 128) {
        const float inv_n = 1.0f / (float)N_NODES;
        float mean = stats[t] * inv_n;
        float var  = stats[128 + t] * inv_n - mean * mean;
        var = fmaxf(var, 0.0f);
        float rstd = rsqrtf(var + 1e-5f);
        float s = rstd * gamma[t];
        sc[t] = s;
        bi[t] = beta[t] - mean * s;
    }
    __syncthreads();
    int idx4 = blockIdx.x * 256 + t;
    int base = idx4 * 4;
    if (base < N_NODES * D) {
        float4 hv = *(const float4*)&h[base];
        float4 av = *(const float4*)&agg[base];
        int c = base & 127;
        float4 o;
        o.x = fast_softplus(hv.x + av.x * sc[c + 0] + bi[c + 0]);
        o.y = fast_softplus(hv.y + av.y * sc[c + 1] + bi[c + 1]);
        o.z = fast_softplus(hv.z + av.z * sc[c + 2] + bi[c + 2]);
        o.w = fast_softplus(hv.w + av.w * sc[c + 3] + bi[c + 3]);
        *(float4*)&out[base] = o;
    }
}

extern "C" void kernel_launch(void* const* d_in, const int* in_sizes, int n_in,
                              void* d_out, int out_size, void* d_ws, size_t ws_size,
                              hipStream_t stream) {
    const float* h     = (const float*)d_in[0];
    const int*   ei    = (const int*)  d_in[1];
    const float* ef    = (const float*)d_in[2];
    const float* gw    = (const float*)d_in[3];
    const float* gb    = (const float*)d_in[4];
    const float* cw    = (const float*)d_in[5];
    const float* cb    = (const float*)d_in[6];
    const float* gamma = (const float*)d_in[7];
    const float* beta  = (const float*)d_in[8];
    float* out = (float*)d_out;

    // Layout: [agg 25.6M][stats 1K][U: counts 3.2M -> pbI 25.6M][wp2 128K]
    //         [wef 16K][bsum 1K][excl 200K][rank 1.6M][perm 3.2M] ~= 56.4 MB
    float*          agg    = (float*)d_ws;
    float*          stats  = agg + (size_t)N_NODES * D;
    int*            counts = (int*)(stats + 256);            // U base (strided hist)
    unsigned int*   pbI    = (unsigned int*)counts;          // aliases U after scan_final
    char*           afterU = (char*)counts + (size_t)N_NODES * 128 * sizeof(unsigned int);
    __bf16*         wp2    = (__bf16*)afterU;                // 128 KB
    __bf16*         wef    = wp2 + WP2_ELEMS;                // 16 KB
    int*            bsum   = (int*)(wef + WEF_ELEMS);        // 256 ints
    int*            excl   = bsum + 256;                     // 200 KB
    unsigned short* rank   = (unsigned short*)(excl + N_NODES);  // 1.6 MB
    int*            perm   = (int*)(rank + N_EDGES);         // 3.2 MB
    unsigned int*   paI    = (unsigned int*)d_out;           // 25.6 MB scratch until out

    // zero agg | stats | counts (one contiguous region)
    const size_t zero_bytes = ((size_t)N_NODES * D + 256) * sizeof(float)
                            + (size_t)N_NODES * CSTRIDE * sizeof(int);
    hipMemsetAsync(d_ws, 0, zero_bytes, stream);
    prep<<<3413, 256, 0, stream>>>(gw, cw, ei, wp2, wef, counts, rank);
    scan_partials<<<SCAN_BLOCKS, 256, 0, stream>>>(counts, bsum);
    scan_final<<<SCAN_BLOCKS, 256, 0, stream>>>(counts, bsum, excl);
    scatter_gemm<<<SCAT_BLOCKS + GEMM_BLOCKS, 512, 0, stream>>>(
        ei, rank, excl, perm, h, wp2, paI, pbI);
    edge_fuse<<<N_TILES, 512, 0, stream>>>(paI, pbI, perm, ei, ef, wef, gb, cb, agg);
    col_stats<<<784, 256, 0, stream>>>(agg, stats);
    out_softplus<<<N_NODES * D / 4 / 256, 256, 0, stream>>>(
        h, agg, stats, gamma, beta, out);
}